// Round 1
// baseline (854.008 us; speedup 1.0000x reference)
//
#include <hip/hip_runtime.h>
#include <hip/hip_bf16.h>

// Problem constants
#define BB 8
#define NN 2048
#define MM 32768
#define QD 512
#define DRR 256
#define DDL 256
#define DD 512
#define HH 8
#define DHH 64
#define INNERD 512
#define TOPK 8
#define SCALE 0.125f

typedef float f32x4 __attribute__((ext_vector_type(4)));
typedef __bf16 bf16x8 __attribute__((ext_vector_type(8)));

// ---- ws layout (float offsets) ----
// q0p : [8 splits][B][512]  @ 0        (32768)
// e0p : [8 splits][B][256]  @ 32768    (16384)
// ks  : [B][8][512]         @ 49152    (32768)  (atomic, must be zeroed)
// vs  : [B][8][512]         @ 81920    (32768)  (atomic, must be zeroed)
// dist: [B][M]              @ 114688   (262144)
// idx : 64 ints             @ 376832
// wqPerm : bf16 512KB       @ byte 1507584
// woPerm : bf16 512KB       @ byte 2031872
#define OFF_Q0P  0
#define OFF_E0P  32768
#define OFF_KS   49152
#define OFF_VS   81920
#define OFF_DIST 114688
#define OFF_IDX  376832
#define OFF_WQP_BYTES 1507584
#define OFF_WOP_BYTES 2031872

__device__ __forceinline__ unsigned short f2bf(float f) {
  unsigned int u = __float_as_uint(f);
  unsigned int r = (u + 0x7FFFu + ((u >> 16) & 1u)) >> 16;
  return (unsigned short)r;
}
__device__ __forceinline__ float bf2f(unsigned int us) {
  return __uint_as_float(us << 16);
}
__device__ __forceinline__ unsigned int pk2(float a, float b) {
  return (unsigned int)f2bf(a) | ((unsigned int)f2bf(b) << 16);
}
__device__ __forceinline__ void unpk8(uint4 v, float* o) {
  o[0] = bf2f(v.x & 0xffffu); o[1] = bf2f(v.x >> 16);
  o[2] = bf2f(v.y & 0xffffu); o[3] = bf2f(v.y >> 16);
  o[4] = bf2f(v.z & 0xffffu); o[5] = bf2f(v.z >> 16);
  o[6] = bf2f(v.w & 0xffffu); o[7] = bf2f(v.w >> 16);
}

// ---- Weight permute: W (512x512 f32 row-major, [k][n]) -> bf16 MFMA B-frag layout
// frag id f = (kb*32 + nt)*64 + lane; lane holds B[kb*32 + (lane>>4)*8 + j][nt*16 + (lane&15)]
__global__ void k_wprep(const float* __restrict__ W, unsigned short* __restrict__ dst) {
  int f = blockIdx.x * 256 + threadIdx.x;       // 32768 frags
  int lane = f & 63, nt = (f >> 6) & 31, kb = f >> 11;
  int kbase = kb * 32 + (lane >> 4) * 8;
  int n = nt * 16 + (lane & 15);
  unsigned short o8[8];
#pragma unroll
  for (int j = 0; j < 8; ++j) o8[j] = f2bf(W[(size_t)(kbase + j) * 512 + n]);
  uint4 v = make_uint4((unsigned)o8[0] | ((unsigned)o8[1] << 16),
                       (unsigned)o8[2] | ((unsigned)o8[3] << 16),
                       (unsigned)o8[4] | ((unsigned)o8[5] << 16),
                       (unsigned)o8[6] | ((unsigned)o8[7] << 16));
  *(uint4*)(dst + (size_t)f * 8) = v;
}

// ---- q0 partials: q0p[g][b][i] = sum_{c in [g*64,g*64+64)} x[b,0,c]*Wq[c,i]
__global__ void k_q0(const float* __restrict__ x, const float* __restrict__ Wq,
                     float* __restrict__ q0p) {
  int b = blockIdx.x, g = blockIdx.y;
  __shared__ float xs[64];
  int tid = threadIdx.x;  // 512
  if (tid < 64) xs[tid] = x[(size_t)b * NN * QD + g * 64 + tid];
  __syncthreads();
  float acc = 0.f;
  const float* wp = Wq + (size_t)(g * 64) * 512 + tid;
#pragma unroll 8
  for (int c = 0; c < 64; ++c) acc += xs[c] * wp[(size_t)c * 512];
  q0p[g * 4096 + b * 512 + tid] = acc;
}

// ---- e0 partials: e0p[gi][b][r] = sum_{i in chunk} q0[b][i]*We[i][r]
__global__ void k_e0(const float* __restrict__ q0p, const float* __restrict__ We,
                     float* __restrict__ e0p) {
  int b = blockIdx.x, gi = blockIdx.y;
  __shared__ float qs[64];
  int tid = threadIdx.x;  // 256
  if (tid < 64) {
    float s = 0.f;
#pragma unroll
    for (int g = 0; g < 8; ++g) s += q0p[g * 4096 + b * 512 + gi * 64 + tid];
    qs[tid] = s;
  }
  __syncthreads();
  float acc = 0.f;
  const float* wp = We + (size_t)(gi * 64) * 256 + tid;
#pragma unroll 8
  for (int c = 0; c < 64; ++c) acc += qs[c] * wp[(size_t)c * 256];
  e0p[gi * 2048 + b * 256 + tid] = acc;
}

// ---- dist^2: one wave per context row, float4/lane over first 256 dims
__global__ void k_dist(const float* __restrict__ ctx, const float* __restrict__ e0p,
                       float* __restrict__ dist) {
  __shared__ float es[256];
  int tid = threadIdx.x;  // 256
  int row0 = blockIdx.x * 4;
  int b = row0 >> 15;
  {
    float s = 0.f;
#pragma unroll
    for (int g = 0; g < 8; ++g) s += e0p[g * 2048 + b * 256 + tid];
    es[tid] = s;
  }
  __syncthreads();
  int w = tid >> 6, l = tid & 63;
  int row = row0 + w;
  float4 c = ((const float4*)(ctx + (size_t)row * DD))[l];
  float4 e = ((const float4*)es)[l];
  float dx = c.x - e.x, dy = c.y - e.y, dz = c.z - e.z, dw = c.w - e.w;
  float s = dx * dx + dy * dy + dz * dz + dw * dw;
#pragma unroll
  for (int m = 1; m < 64; m <<= 1) s += __shfl_xor(s, m, 64);
  if (l == 0) dist[row] = s;
}

// ---- top-8 smallest (ties -> lower index); set semantics are all that matter
__global__ void k_topk(const float* __restrict__ dist, int* __restrict__ idxo) {
  int b = blockIdx.x, tid = threadIdx.x;  // 256
  const float* dp = dist + (size_t)b * MM;
  float lv[8]; int li[8];
#pragma unroll
  for (int i = 0; i < 8; ++i) { lv[i] = INFINITY; li[i] = 1 << 30; }
  for (int t = 0; t < MM / 256; ++t) {
    int m = t * 256 + tid;
    float v = dp[m];
    if (v < lv[7]) {
      int p = 7;
      while (p > 0 && lv[p - 1] > v) { lv[p] = lv[p - 1]; li[p] = li[p - 1]; --p; }
      lv[p] = v; li[p] = m;
    }
  }
  __shared__ float wvs[4];
  __shared__ int wis[4];
  __shared__ int winS;
  int head = 0;
  for (int r = 0; r < 8; ++r) {
    float cv = (head < 8) ? lv[head] : INFINITY;
    int ci = (head < 8) ? li[head] : (1 << 30);
#pragma unroll
    for (int m = 1; m < 64; m <<= 1) {
      float ov = __shfl_xor(cv, m, 64);
      int oi = __shfl_xor(ci, m, 64);
      if (ov < cv || (ov == cv && oi < ci)) { cv = ov; ci = oi; }
    }
    int w = tid >> 6;
    if ((tid & 63) == 0) { wvs[w] = cv; wis[w] = ci; }
    __syncthreads();
    if (tid == 0) {
      float bv = wvs[0]; int bi = wis[0];
#pragma unroll
      for (int k = 1; k < 4; ++k)
        if (wvs[k] < bv || (wvs[k] == bv && wis[k] < bi)) { bv = wvs[k]; bi = wis[k]; }
      winS = bi;
      idxo[b * 8 + r] = bi;
    }
    __syncthreads();
    if (head < 8 && li[head] == winS) ++head;
    __syncthreads();
  }
}

// ---- k = labels@Wk, v = reps@Wv for the 8 gathered rows (split over c, atomics)
__global__ void k_kv(const float* __restrict__ ctx, const int* __restrict__ idx,
                     const float* __restrict__ Wk, const float* __restrict__ Wv,
                     float* __restrict__ ks, float* __restrict__ vs) {
  int b = blockIdx.x, ic = blockIdx.y, cc = blockIdx.z;  // (8,4,4), 128 thr
  int tid = threadIdx.x;
  __shared__ float rep[8][64], lab[8][64];
  __shared__ int ids[8];
  if (tid < 8) ids[tid] = idx[b * 8 + tid];
  __syncthreads();
  for (int e = tid; e < 512; e += 128) {
    int j = e >> 6, c = e & 63;
    const float* rowp = ctx + ((size_t)b * MM + ids[j]) * DD + cc * 64;
    rep[j][c] = rowp[c];
    lab[j][c] = rowp[256 + c];
  }
  __syncthreads();
  int i = ic * 128 + tid;
  float ka[8] = {0, 0, 0, 0, 0, 0, 0, 0}, va[8] = {0, 0, 0, 0, 0, 0, 0, 0};
  for (int c = 0; c < 64; ++c) {
    float wk = Wk[(size_t)(cc * 64 + c) * 512 + i];
    float wv = Wv[(size_t)(cc * 64 + c) * 512 + i];
#pragma unroll
    for (int j = 0; j < 8; ++j) { ka[j] += lab[j][c] * wk; va[j] += rep[j][c] * wv; }
  }
#pragma unroll
  for (int j = 0; j < 8; ++j) {
    atomicAdd(&ks[((size_t)b * 8 + j) * 512 + i], ka[j]);
    atomicAdd(&vs[((size_t)b * 8 + j) * 512 + i], va[j]);
  }
}

// ---- fused: Q = x@Wq (MFMA) -> attention (per token/head) -> out = o@Wout + bout (MFMA)
// 32 tokens/block, 256 threads (4 waves, n-split 128 cols each)
__device__ __forceinline__ void gemm512(const unsigned short* aT, const unsigned short* wP,
                                        int w, int l, f32x4 (&acc)[2][8]) {
  int quad = l >> 4, lcol = l & 15;
#pragma unroll 4
  for (int kb = 0; kb < 16; ++kb) {
    uint4 a0 = *(const uint4*)(aT + (size_t)lcol * 520 + kb * 32 + quad * 8);
    uint4 a1 = *(const uint4*)(aT + (size_t)(16 + lcol) * 520 + kb * 32 + quad * 8);
    bf16x8 af0 = __builtin_bit_cast(bf16x8, a0);
    bf16x8 af1 = __builtin_bit_cast(bf16x8, a1);
    const uint4* bp = (const uint4*)(wP + ((size_t)(kb * 32 + w * 8) * 64 + l) * 8);
#pragma unroll
    for (int t = 0; t < 8; ++t) {
      bf16x8 bf = __builtin_bit_cast(bf16x8, bp[(size_t)t * 64]);
      acc[0][t] = __builtin_amdgcn_mfma_f32_16x16x32_bf16(af0, bf, acc[0][t], 0, 0, 0);
      acc[1][t] = __builtin_amdgcn_mfma_f32_16x16x32_bf16(af1, bf, acc[1][t], 0, 0, 0);
    }
  }
}

__global__ __launch_bounds__(256, 2) void k_fused(
    const float* __restrict__ x, const unsigned short* __restrict__ wqP,
    const unsigned short* __restrict__ woP, const float* __restrict__ ks,
    const float* __restrict__ vs, const float* __restrict__ bout,
    float* __restrict__ out) {
  __shared__ unsigned short aT[32 * 520];       // x -> Q -> o (bf16, padded rows)
  __shared__ unsigned short ksl[8 * 520];       // [h][j*64+d] bf16, h-stride 520
  __shared__ unsigned short vsl[8 * 520];
  int tid = threadIdx.x;
  int tok0 = blockIdx.x * 32;
  int b = tok0 >> 11;

  // stage k,v -> bf16 LDS
  for (int e = tid; e < 4096; e += 256) {
    int j = e >> 9, i = e & 511;
    int h = i >> 6, d = i & 63;
    ksl[h * 520 + j * 64 + d] = f2bf(ks[((size_t)b * 8 + j) * 512 + i]);
    vsl[h * 520 + j * 64 + d] = f2bf(vs[((size_t)b * 8 + j) * 512 + i]);
  }
  // stage x tile -> aT (bf16, row-major padded)
#pragma unroll
  for (int it = 0; it < 8; ++it) {
    int g = it * 256 + tid;
    int k8 = g & 63, m = g >> 6;
    const float* xp = x + ((size_t)(tok0 + m)) * 512 + k8 * 8;
    float4 a = ((const float4*)xp)[0];
    float4 c = ((const float4*)xp)[1];
    uint4 pk = make_uint4(pk2(a.x, a.y), pk2(a.z, a.w), pk2(c.x, c.y), pk2(c.z, c.w));
    *(uint4*)(aT + (size_t)m * 520 + k8 * 8) = pk;
  }
  __syncthreads();

  int w = tid >> 6, l = tid & 63;
  int quad = l >> 4, lcol = l & 15;
  f32x4 acc[2][8];
#pragma unroll
  for (int mt = 0; mt < 2; ++mt)
#pragma unroll
    for (int t = 0; t < 8; ++t) acc[mt][t] = (f32x4){0.f, 0.f, 0.f, 0.f};

  gemm512(aT, wqP, w, l, acc);          // Q in acc (fp32)
  __syncthreads();                      // all waves done reading x from aT

  // write Q (bf16) back into aT; C/D layout: row=quad*4+reg, col=lane&15
#pragma unroll
  for (int mt = 0; mt < 2; ++mt)
#pragma unroll
    for (int t = 0; t < 8; ++t)
#pragma unroll
      for (int r = 0; r < 4; ++r) {
        int mrow = mt * 16 + quad * 4 + r;
        int col = w * 128 + t * 16 + lcol;
        aT[(size_t)mrow * 520 + col] = f2bf(acc[mt][t][r]);
      }
  __syncthreads();

  // attention: thread -> (token m, head h); reads/writes only its own 64-col strip
  {
    int m = tid >> 3, h = tid & 7;
    float sim[8] = {0, 0, 0, 0, 0, 0, 0, 0};
#pragma unroll
    for (int dc0 = 0; dc0 < 4; ++dc0) {
      int dc = (dc0 + h) & 3;                       // rotate to spread LDS banks
      float qf[16];
      const uint4* qp = (const uint4*)(aT + (size_t)m * 520 + h * 64 + dc * 16);
      unpk8(qp[0], qf); unpk8(qp[1], qf + 8);
#pragma unroll
      for (int j = 0; j < 8; ++j) {
        const uint4* kp = (const uint4*)(ksl + (size_t)h * 520 + j * 64 + dc * 16);
        float kf[16];
        unpk8(kp[0], kf); unpk8(kp[1], kf + 8);
        float s = 0.f;
#pragma unroll
        for (int i = 0; i < 16; ++i) s += qf[i] * kf[i];
        sim[j] += s;
      }
    }
    float z[8], mx = -INFINITY;
#pragma unroll
    for (int j = 0; j < 8; ++j) { z[j] = sim[j] * SCALE; mx = fmaxf(mx, z[j]); }
    float p[8], psum = 0.f;
#pragma unroll
    for (int j = 0; j < 8; ++j) { p[j] = __expf(z[j] - mx); psum += p[j]; }
    float inv = 1.f / psum;
#pragma unroll
    for (int j = 0; j < 8; ++j) p[j] *= inv;
#pragma unroll
    for (int dc0 = 0; dc0 < 4; ++dc0) {
      int dc = (dc0 + h) & 3;
      float o16[16];
#pragma unroll
      for (int i = 0; i < 16; ++i) o16[i] = 0.f;
#pragma unroll
      for (int j = 0; j < 8; ++j) {
        const uint4* vp = (const uint4*)(vsl + (size_t)h * 520 + j * 64 + dc * 16);
        float vf[16];
        unpk8(vp[0], vf); unpk8(vp[1], vf + 8);
#pragma unroll
        for (int i = 0; i < 16; ++i) o16[i] += p[j] * vf[i];
      }
      uint4 o0 = make_uint4(pk2(o16[0], o16[1]), pk2(o16[2], o16[3]),
                            pk2(o16[4], o16[5]), pk2(o16[6], o16[7]));
      uint4 o1 = make_uint4(pk2(o16[8], o16[9]), pk2(o16[10], o16[11]),
                            pk2(o16[12], o16[13]), pk2(o16[14], o16[15]));
      uint4* op = (uint4*)(aT + (size_t)m * 520 + h * 64 + dc * 16);
      op[0] = o0; op[1] = o1;
    }
  }
  __syncthreads();

  // GEMM2: out = o @ Wout + bout
#pragma unroll
  for (int mt = 0; mt < 2; ++mt)
#pragma unroll
    for (int t = 0; t < 8; ++t) acc[mt][t] = (f32x4){0.f, 0.f, 0.f, 0.f};
  gemm512(aT, woP, w, l, acc);

#pragma unroll
  for (int t = 0; t < 8; ++t) {
    int col = w * 128 + t * 16 + lcol;
    float bb = bout[col];
#pragma unroll
    for (int mt = 0; mt < 2; ++mt)
#pragma unroll
      for (int r = 0; r < 4; ++r) {
        int mrow = mt * 16 + quad * 4 + r;
        out[((size_t)(tok0 + mrow)) * 512 + col] = acc[mt][t][r] + bb;
      }
  }
}

extern "C" void kernel_launch(void* const* d_in, const int* in_sizes, int n_in,
                              void* d_out, int out_size, void* d_ws, size_t ws_size,
                              hipStream_t stream) {
  const float* x    = (const float*)d_in[0];
  const float* ctx  = (const float*)d_in[1];
  const float* Wq   = (const float*)d_in[2];
  const float* Wk   = (const float*)d_in[3];
  const float* Wv   = (const float*)d_in[4];
  const float* We   = (const float*)d_in[5];
  const float* Wout = (const float*)d_in[6];
  const float* bout = (const float*)d_in[7];
  float* out = (float*)d_out;
  float* ws = (float*)d_ws;

  float* q0p  = ws + OFF_Q0P;
  float* e0p  = ws + OFF_E0P;
  float* ks   = ws + OFF_KS;
  float* vs   = ws + OFF_VS;
  float* dist = ws + OFF_DIST;
  int*   idx  = (int*)(ws + OFF_IDX);
  unsigned short* wqP = (unsigned short*)((char*)d_ws + OFF_WQP_BYTES);
  unsigned short* woP = (unsigned short*)((char*)d_ws + OFF_WOP_BYTES);

  // zero atomic accumulators (ks, vs)
  hipMemsetAsync((char*)d_ws + (size_t)OFF_KS * 4, 0, (size_t)65536 * 4, stream);

  k_wprep<<<128, 256, 0, stream>>>(Wq, wqP);
  k_wprep<<<128, 256, 0, stream>>>(Wout, woP);
  k_q0<<<dim3(8, 8), 512, 0, stream>>>(x, Wq, q0p);
  k_e0<<<dim3(8, 8), 256, 0, stream>>>(q0p, We, e0p);
  k_dist<<<65536, 256, 0, stream>>>(ctx, e0p, dist);
  k_topk<<<8, 256, 0, stream>>>(dist, idx);
  k_kv<<<dim3(8, 4, 4), 128, 0, stream>>>(ctx, idx, Wk, Wv, ks, vs);
  k_fused<<<512, 256, 0, stream>>>(x, wqP, woP, ks, vs, bout, out);
}